// Round 1
// baseline (551.744 us; speedup 1.0000x reference)
//
#include <hip/hip_runtime.h>

typedef unsigned short u16;
typedef unsigned int u32;
typedef __attribute__((ext_vector_type(8))) short short8;
typedef __attribute__((ext_vector_type(8))) u16 u16x8;
typedef __attribute__((ext_vector_type(4))) u32 u32x4;
typedef __attribute__((ext_vector_type(4))) float f32x4;

#define NB 16
#define CC 256
#define HW 3136
#define NT 49

// round-to-nearest-even f32 -> bf16 bits
__device__ __forceinline__ u16 f2bf(float x) {
  u32 u = __float_as_uint(x);
  u += 0x7fffu + ((u >> 16) & 1u);
  return (u16)(u >> 16);
}

__device__ __forceinline__ f32x4 mfma16(short8 a, short8 b, f32x4 c) {
  return __builtin_amdgcn_mfma_f32_16x16x32_bf16(a, b, c, 0, 0, 0);
}

// ---------------- P0: W f32 -> bf16 ----------------
__global__ __launch_bounds__(256) void k_cvtw(const float* __restrict__ W,
                                              u16* __restrict__ Wbf) {
  int i = (blockIdx.x * 256 + threadIdx.x) * 4;
  f32x4 v = *(const f32x4*)(W + i);
  u32 lo = (u32)f2bf(v[0]) | ((u32)f2bf(v[1]) << 16);
  u32 hi = (u32)f2bf(v[2]) | ((u32)f2bf(v[3]) << 16);
  *(u32*)(Wbf + i) = lo;
  *(u32*)(Wbf + i + 2) = hi;
}

// ---------------- P1: feat -> f_bf [N][HW][C] (normalized, bf16) + norms ----
__global__ __launch_bounds__(256) void k_prep_f(const float* __restrict__ feat,
                                                u16* __restrict__ f_bf,
                                                float* __restrict__ norm_f) {
  int pt = blockIdx.x, n = blockIdx.y;
  int tid = threadIdx.x;
  __shared__ float tile[256][65];  // +1 pad: conflict-free column sums
  __shared__ float rinv[64];
  const float* src = feat + (size_t)n * CC * HW + pt * 64;
  int p = tid & 63;
  #pragma unroll 8
  for (int c = tid >> 6; c < 256; c += 4)
    tile[c][p] = src[(size_t)c * HW + p];
  __syncthreads();
  if (tid < 64) {
    float s = 0.f;
    #pragma unroll 16
    for (int c = 0; c < 256; ++c) { float v = tile[c][tid]; s += v * v; }
    float nv = fmaxf(sqrtf(s), 1e-12f);
    rinv[tid] = 1.0f / nv;
    norm_f[n * HW + pt * 64 + tid] = nv;  // clamped norm (exact factorization)
  }
  __syncthreads();
  u16* dst = f_bf + ((size_t)n * HW + pt * 64) * 256;
  #pragma unroll
  for (int j = 0; j < 8; ++j) {
    int chunk = j * 256 + tid;     // 0..2047 ; contiguous 16B global writes
    int pp = chunk >> 5;
    int c0 = (chunk & 31) * 8;
    float inv = rinv[pp];
    u16x8 o;
    #pragma unroll
    for (int k = 0; k < 8; ++k) o[k] = f2bf(tile[c0 + k][pp] * inv);
    *(u16x8*)(dst + pp * 256 + c0) = o;
  }
}

// ---------------- P2: fv = l2norm_o( norm_f * (Wbf . f) + b ) -> [N][C][HW] --
__global__ __launch_bounds__(256) void k_conv(const u16* __restrict__ Wbf,
                                              const float* __restrict__ bias,
                                              const u16* __restrict__ f_bf,
                                              const float* __restrict__ norm_f,
                                              u16* __restrict__ fv_bf) {
  int qt = blockIdx.x, n = blockIdx.y;
  int tid = threadIdx.x;
  int lane = tid & 63, w = tid >> 6;
  int lr = lane & 15, lg = lane >> 4;
  __shared__ __align__(16) char fq[32768];   // [64 q][256 c] bf16, swizzled
  __shared__ float wred[4][64];
  __shared__ float sinv[64];

  const char* fsrc = (const char*)(f_bf + ((size_t)n * HW + qt * 64) * 256);
  #pragma unroll
  for (int rep = 0; rep < 8; ++rep) {
    int linear = rep * 4096 + tid * 16;
    int q = linear >> 9;
    int cb = linear & 0x1F0;
    u32x4 v = *(const u32x4*)(fsrc + q * 512 + cb);
    *(u32x4*)(fq + q * 512 + (cb ^ ((q & 7) << 4))) = v;
  }
  __syncthreads();

  f32x4 acc[4][4] = {};
  #pragma unroll
  for (int kk = 0; kk < 8; ++kk) {
    short8 bfr[4], afr[4];
    #pragma unroll
    for (int j = 0; j < 4; ++j) {
      int q = j * 16 + lr;
      bfr[j] = *(const short8*)(fq + q * 512 + ((kk * 64 + lg * 16) ^ ((q & 7) << 4)));
    }
    #pragma unroll
    for (int i = 0; i < 4; ++i) {
      int o = w * 64 + i * 16 + lr;
      afr[i] = *(const short8*)((const char*)Wbf + (size_t)o * 512 + kk * 64 + lg * 16);
    }
    #pragma unroll
    for (int i = 0; i < 4; ++i)
      #pragma unroll
      for (int j = 0; j < 4; ++j)
        acc[i][j] = mfma16(afr[i], bfr[j], acc[i][j]);
  }

  float nf[4];
  #pragma unroll
  for (int j = 0; j < 4; ++j) nf[j] = norm_f[n * HW + qt * 64 + j * 16 + lr];
  float partial[4] = {0.f, 0.f, 0.f, 0.f};
  #pragma unroll
  for (int i = 0; i < 4; ++i)
    #pragma unroll
    for (int r = 0; r < 4; ++r) {
      float bv = bias[w * 64 + i * 16 + lg * 4 + r];
      #pragma unroll
      for (int j = 0; j < 4; ++j) {
        float pre = acc[i][j][r] * nf[j] + bv;
        acc[i][j][r] = pre;
        partial[j] += pre * pre;
      }
    }
  #pragma unroll
  for (int j = 0; j < 4; ++j) {
    float v = partial[j];
    v += __shfl_xor(v, 16);
    v += __shfl_xor(v, 32);
    if (lane < 16) wred[w][j * 16 + lane] = v;  // deterministic reduction
  }
  __syncthreads();
  if (tid < 64) {
    float s = wred[0][tid] + wred[1][tid] + wred[2][tid] + wred[3][tid];
    sinv[tid] = 1.0f / fmaxf(sqrtf(s), 1e-12f);
  }
  __syncthreads();
  u16* dst = fv_bf + (size_t)n * CC * HW + qt * 64;
  #pragma unroll
  for (int i = 0; i < 4; ++i)
    #pragma unroll
    for (int r = 0; r < 4; ++r) {
      int o = w * 64 + i * 16 + lg * 4 + r;
      #pragma unroll
      for (int j = 0; j < 4; ++j) {
        int q = j * 16 + lr;
        dst[(size_t)o * HW + q] = f2bf(acc[i][j][r] * sinv[q]);
      }
    }
}

// ---------------- P3: fused attention: out = FV . (relu(f^T f)^2)^T ---------
__global__ __launch_bounds__(256, 2) void k_attn(const u16* __restrict__ f_bf,
                                                 const u16* __restrict__ fv_bf,
                                                 float* __restrict__ out) {
  // XCD-aware swizzle: each XCD's L2 sees only 2 batches (6.4 MB reuse set)
  int linear = blockIdx.y * NT + blockIdx.x;
  int vb = (linear & 7) * 98 + (linear >> 3);
  int n = vb / NT;
  int pt = vb - n * NT;

  int tid = threadIdx.x;
  int lane = tid & 63, w = tid >> 6;
  int lr = lane & 15, lg = lane >> 4;
  int wp = w & 1, wq = w >> 1;
  __shared__ __align__(16) char fq[32768];   // [64 q][256 c] bf16 swizzled
  __shared__ __align__(16) char fvt[32768];  // [256 c][64 q] bf16 swizzled
  __shared__ __align__(16) char attl[8192];  // [64 p][64 q] bf16 swizzled

  const char* fbase = (const char*)f_bf + (size_t)n * HW * 512;
  const char* fvbase = (const char*)fv_bf + (size_t)n * CC * HW * 2;

  // f_p fragments in registers: wave covers p rows [wp*32, wp*32+32)
  short8 ap[2][8];
  #pragma unroll
  for (int fi = 0; fi < 2; ++fi) {
    int p = pt * 64 + wp * 32 + fi * 16 + lr;
    #pragma unroll
    for (int kk = 0; kk < 8; ++kk)
      ap[fi][kk] = *(const short8*)(fbase + (size_t)p * 512 + kk * 64 + lg * 16);
  }

  f32x4 oacc[4][4] = {};  // [c-frag][p-frag], wave w owns c rows [w*64, w*64+64)

  for (int qt = 0; qt < NT; ++qt) {
    __syncthreads();  // protect fq/fvt/attl from previous iteration readers
    // stage f_q tile
    const char* fsrc = fbase + (size_t)qt * 64 * 512;
    #pragma unroll
    for (int rep = 0; rep < 8; ++rep) {
      int lin = rep * 4096 + tid * 16;
      int q = lin >> 9;
      int cb = lin & 0x1F0;
      u32x4 v = *(const u32x4*)(fsrc + q * 512 + cb);
      *(u32x4*)(fq + q * 512 + (cb ^ ((q & 7) << 4))) = v;
    }
    // stage fvt tile
    #pragma unroll
    for (int rep = 0; rep < 8; ++rep) {
      int lin = rep * 4096 + tid * 16;
      int c = lin >> 7;
      int cb = lin & 0x70;
      u32x4 v = *(const u32x4*)(fvbase + (size_t)c * (HW * 2) + qt * 128 + cb);
      *(u32x4*)(fvt + c * 128 + (cb ^ ((c & 7) << 4))) = v;
    }
    __syncthreads();

    // GEMM1: S[p,q] = sum_c f_p f_q  (2x2 wave tiling)
    f32x4 s[2][2] = {};
    #pragma unroll
    for (int kk = 0; kk < 8; ++kk) {
      short8 bq[2];
      #pragma unroll
      for (int fj = 0; fj < 2; ++fj) {
        int q = wq * 32 + fj * 16 + lr;
        bq[fj] = *(const short8*)(fq + q * 512 + ((kk * 64 + lg * 16) ^ ((q & 7) << 4)));
      }
      s[0][0] = mfma16(ap[0][kk], bq[0], s[0][0]);
      s[0][1] = mfma16(ap[0][kk], bq[1], s[0][1]);
      s[1][0] = mfma16(ap[1][kk], bq[0], s[1][0]);
      s[1][1] = mfma16(ap[1][kk], bq[1], s[1][1]);
    }
    // relu^2 -> bf16 -> attl
    #pragma unroll
    for (int fi = 0; fi < 2; ++fi)
      #pragma unroll
      for (int fj = 0; fj < 2; ++fj)
        #pragma unroll
        for (int r = 0; r < 4; ++r) {
          float v = s[fi][fj][r];
          v = fmaxf(v, 0.f);
          v = v * v;
          int p = wp * 32 + fi * 16 + lg * 4 + r;
          int q = wq * 32 + fj * 16 + lr;
          *(u16*)(attl + p * 128 + ((q * 2) ^ ((p & 7) << 4))) = f2bf(v);
        }
    __syncthreads();

    // GEMM2: out[c,p] += sum_q FVT[c,q] * ATT[p,q]
    #pragma unroll
    for (int kk = 0; kk < 2; ++kk) {
      short8 av[4], bt[4];
      #pragma unroll
      for (int fi = 0; fi < 4; ++fi) {
        int c = w * 64 + fi * 16 + lr;
        av[fi] = *(const short8*)(fvt + c * 128 + ((kk * 64 + lg * 16) ^ ((c & 7) << 4)));
      }
      #pragma unroll
      for (int fp = 0; fp < 4; ++fp) {
        int p = fp * 16 + lr;
        bt[fp] = *(const short8*)(attl + p * 128 + ((kk * 64 + lg * 16) ^ ((p & 7) << 4)));
      }
      #pragma unroll
      for (int fi = 0; fi < 4; ++fi)
        #pragma unroll
        for (int fp = 0; fp < 4; ++fp)
          oacc[fi][fp] = mfma16(av[fi], bt[fp], oacc[fi][fp]);
    }
  }

  // epilogue: out[n][c][pt*64 + p]
  float* op = out + (size_t)n * CC * HW + pt * 64;
  #pragma unroll
  for (int fi = 0; fi < 4; ++fi)
    #pragma unroll
    for (int r = 0; r < 4; ++r) {
      int c = w * 64 + fi * 16 + lg * 4 + r;
      #pragma unroll
      for (int fp = 0; fp < 4; ++fp)
        op[(size_t)c * HW + fp * 16 + lr] = oacc[fi][fp][r];
    }
}

extern "C" void kernel_launch(void* const* d_in, const int* in_sizes, int n_in,
                              void* d_out, int out_size, void* d_ws, size_t ws_size,
                              hipStream_t stream) {
  const float* feat = (const float*)d_in[0];
  const float* W    = (const float*)d_in[1];
  const float* bias = (const float*)d_in[2];
  float* out = (float*)d_out;

  char* ws = (char*)d_ws;
  // ws layout (all 256B aligned): Wbf 128KB | norm_f 196KB | f_bf 24.5MB | fv_bf 24.5MB
  u16*   Wbf    = (u16*)ws;
  float* norm_f = (float*)(ws + 131072);
  u16*   f_bf   = (u16*)(ws + 331776);
  u16*   fv_bf  = (u16*)(ws + 26021888);

  k_cvtw<<<dim3(64), dim3(256), 0, stream>>>(W, Wbf);
  k_prep_f<<<dim3(NT, NB), dim3(256), 0, stream>>>(feat, f_bf, norm_f);
  k_conv<<<dim3(NT, NB), dim3(256), 0, stream>>>(Wbf, bias, f_bf, norm_f, fv_bf);
  k_attn<<<dim3(NT, NB), dim3(256), 0, stream>>>(f_bf, fv_bf, out);
}

// Round 2
// 308.305 us; speedup vs baseline: 1.7896x; 1.7896x over previous
//
#include <hip/hip_runtime.h>

typedef unsigned short u16;
typedef unsigned int u32;
typedef __attribute__((ext_vector_type(8))) short short8;
typedef __attribute__((ext_vector_type(8))) u16 u16x8;
typedef __attribute__((ext_vector_type(4))) u32 u32x4;
typedef __attribute__((ext_vector_type(4))) float f32x4;

#define NB 16
#define CC 256
#define HW 3136
#define NT 49

// round-to-nearest-even f32 -> bf16 bits
__device__ __forceinline__ u16 f2bf(float x) {
  u32 u = __float_as_uint(x);
  u += 0x7fffu + ((u >> 16) & 1u);
  return (u16)(u >> 16);
}

__device__ __forceinline__ f32x4 mfma16(short8 a, short8 b, f32x4 c) {
  return __builtin_amdgcn_mfma_f32_16x16x32_bf16(a, b, c, 0, 0, 0);
}

// async global->LDS, 16B per lane; lds dest = base + lane*16 (wave-uniform base)
__device__ __forceinline__ void gl_lds16(const void* g, void* l) {
  __builtin_amdgcn_global_load_lds(
      (const __attribute__((address_space(1))) void*)g,
      (__attribute__((address_space(3))) void*)l, 16, 0, 0);
}

// ---------------- P0: W f32 -> bf16 ----------------
__global__ __launch_bounds__(256) void k_cvtw(const float* __restrict__ W,
                                              u16* __restrict__ Wbf) {
  int i = (blockIdx.x * 256 + threadIdx.x) * 4;
  f32x4 v = *(const f32x4*)(W + i);
  u32 lo = (u32)f2bf(v[0]) | ((u32)f2bf(v[1]) << 16);
  u32 hi = (u32)f2bf(v[2]) | ((u32)f2bf(v[3]) << 16);
  *(u32*)(Wbf + i) = lo;
  *(u32*)(Wbf + i + 2) = hi;
}

// ---------------- P1: feat -> f_bf [N][HW][C] (normalized, bf16) + norms ----
__global__ __launch_bounds__(256) void k_prep_f(const float* __restrict__ feat,
                                                u16* __restrict__ f_bf,
                                                float* __restrict__ norm_f) {
  int pt = blockIdx.x, n = blockIdx.y;
  int tid = threadIdx.x;
  __shared__ float tile[256][65];  // +1 pad: conflict-free column sums
  __shared__ float rinv[64];
  const float* src = feat + (size_t)n * CC * HW + pt * 64;
  int p = tid & 63;
  #pragma unroll 8
  for (int c = tid >> 6; c < 256; c += 4)
    tile[c][p] = src[(size_t)c * HW + p];
  __syncthreads();
  if (tid < 64) {
    float s = 0.f;
    #pragma unroll 16
    for (int c = 0; c < 256; ++c) { float v = tile[c][tid]; s += v * v; }
    float nv = fmaxf(sqrtf(s), 1e-12f);
    rinv[tid] = 1.0f / nv;
    norm_f[n * HW + pt * 64 + tid] = nv;  // clamped norm (exact factorization)
  }
  __syncthreads();
  u16* dst = f_bf + ((size_t)n * HW + pt * 64) * 256;
  #pragma unroll
  for (int j = 0; j < 8; ++j) {
    int chunk = j * 256 + tid;     // contiguous 16B global writes
    int pp = chunk >> 5;
    int c0 = (chunk & 31) * 8;
    float inv = rinv[pp];
    u16x8 o;
    #pragma unroll
    for (int k = 0; k < 8; ++k) o[k] = f2bf(tile[c0 + k][pp] * inv);
    *(u16x8*)(dst + pp * 256 + c0) = o;
  }
}

// ---------------- P2: fv = l2norm_o( norm_f * (Wbf . f) + b ) -> [N][C][HW] --
__global__ __launch_bounds__(256) void k_conv(const u16* __restrict__ Wbf,
                                              const float* __restrict__ bias,
                                              const u16* __restrict__ f_bf,
                                              const float* __restrict__ norm_f,
                                              u16* __restrict__ fv_bf) {
  int qt = blockIdx.x, n = blockIdx.y;
  int tid = threadIdx.x;
  int lane = tid & 63, w = tid >> 6;
  int lr = lane & 15, lg = lane >> 4;
  __shared__ __align__(16) char fq[32768];   // [64 q][256 c] bf16, swizzled
  __shared__ float wred[4][64];
  __shared__ float sinv[64];

  const char* fsrc = (const char*)(f_bf + ((size_t)n * HW + qt * 64) * 256);
  #pragma unroll
  for (int rep = 0; rep < 8; ++rep) {
    int linear = rep * 4096 + tid * 16;
    int q = linear >> 9;
    int cb = linear & 0x1F0;
    u32x4 v = *(const u32x4*)(fsrc + q * 512 + cb);
    *(u32x4*)(fq + q * 512 + (cb ^ ((q & 7) << 4))) = v;
  }
  __syncthreads();

  f32x4 acc[4][4] = {};
  #pragma unroll
  for (int kk = 0; kk < 8; ++kk) {
    short8 bfr[4], afr[4];
    #pragma unroll
    for (int j = 0; j < 4; ++j) {
      int q = j * 16 + lr;
      bfr[j] = *(const short8*)(fq + q * 512 + ((kk * 64 + lg * 16) ^ ((q & 7) << 4)));
    }
    #pragma unroll
    for (int i = 0; i < 4; ++i) {
      int o = w * 64 + i * 16 + lr;
      afr[i] = *(const short8*)((const char*)Wbf + (size_t)o * 512 + kk * 64 + lg * 16);
    }
    #pragma unroll
    for (int i = 0; i < 4; ++i)
      #pragma unroll
      for (int j = 0; j < 4; ++j)
        acc[i][j] = mfma16(afr[i], bfr[j], acc[i][j]);
  }

  float nf[4];
  #pragma unroll
  for (int j = 0; j < 4; ++j) nf[j] = norm_f[n * HW + qt * 64 + j * 16 + lr];
  float partial[4] = {0.f, 0.f, 0.f, 0.f};
  #pragma unroll
  for (int i = 0; i < 4; ++i)
    #pragma unroll
    for (int r = 0; r < 4; ++r) {
      float bv = bias[w * 64 + i * 16 + lg * 4 + r];
      #pragma unroll
      for (int j = 0; j < 4; ++j) {
        float pre = acc[i][j][r] * nf[j] + bv;
        acc[i][j][r] = pre;
        partial[j] += pre * pre;
      }
    }
  #pragma unroll
  for (int j = 0; j < 4; ++j) {
    float v = partial[j];
    v += __shfl_xor(v, 16);
    v += __shfl_xor(v, 32);
    if (lane < 16) wred[w][j * 16 + lane] = v;  // deterministic reduction
  }
  __syncthreads();
  if (tid < 64) {
    float s = wred[0][tid] + wred[1][tid] + wred[2][tid] + wred[3][tid];
    sinv[tid] = 1.0f / fmaxf(sqrtf(s), 1e-12f);
  }
  __syncthreads();
  u16* dst = fv_bf + (size_t)n * CC * HW + qt * 64;
  #pragma unroll
  for (int i = 0; i < 4; ++i)
    #pragma unroll
    for (int r = 0; r < 4; ++r) {
      int o = w * 64 + i * 16 + lg * 4 + r;
      #pragma unroll
      for (int j = 0; j < 4; ++j) {
        int q = j * 16 + lr;
        dst[(size_t)o * HW + q] = f2bf(acc[i][j][r] * sinv[q]);
      }
    }
}

// ---------------- P3: fused attention: out = FV . (relu(f^T f)^2)^T ---------
// Pipelined: fq double-buffered via global_load_lds (pre-swizzled source),
// fv fragments read directly from L2 via asm loads (deterministic vmcnt),
// raw s_barrier + counted waits so prefetch stays in flight across barriers.
__global__ __launch_bounds__(256, 2) void k_attn(const u16* __restrict__ f_bf,
                                                 const u16* __restrict__ fv_bf,
                                                 float* __restrict__ out) {
  // XCD-aware swizzle: each XCD's L2 sees only 2 batches
  int linear = blockIdx.y * NT + blockIdx.x;
  int vb = (linear & 7) * 98 + (linear >> 3);
  int n = vb / NT;
  int pt = vb - n * NT;

  int tid = threadIdx.x;
  int lane = tid & 63, w = tid >> 6;
  int lr = lane & 15, lg = lane >> 4;
  int wp = w & 1, wq = w >> 1;
  __shared__ __align__(16) char fqd[2][32768];  // [64 q][256 c] bf16 swizzled, dbuf
  __shared__ __align__(16) char attl[8192];     // [64 p][64 q] bf16 swizzled

  const char* fbase = (const char*)f_bf + (size_t)n * HW * 512;
  const char* fvbase = (const char*)fv_bf + (size_t)n * CC * HW * 2;

  // per-lane pre-swizzled source offsets: LDS linear dest d = (w*8+r)*1024+lane*16
  // content must satisfy lds[(q*512+cb)^sw_q] = f[q][cb]  (sw involution)
  int so[8];
  #pragma unroll
  for (int r = 0; r < 8; ++r) {
    int q = w * 16 + r * 2 + (lane >> 5);
    int col = (lane & 31) * 16;
    so[r] = q * 512 + (col ^ ((q & 7) << 4));
  }

  // f_p fragments in registers: wave covers p rows [wp*32, wp*32+32)
  short8 ap[2][8];
  #pragma unroll
  for (int fi = 0; fi < 2; ++fi) {
    int p = pt * 64 + wp * 32 + fi * 16 + lr;
    #pragma unroll
    for (int kk = 0; kk < 8; ++kk)
      ap[fi][kk] = *(const short8*)(fbase + (size_t)p * 512 + kk * 64 + lg * 16);
  }

  // prologue: prefetch q-tile 0 into buf 0 (8 x global_load_lds dwordx4)
  #pragma unroll
  for (int r = 0; r < 8; ++r)
    gl_lds16(fbase + so[r], (char*)fqd[0] + (w * 8 + r) * 1024);

  f32x4 oacc[4][4] = {};  // [c-frag][p-frag], wave w owns c rows [w*64, w*64+64)

  for (int qt = 0; qt < NT; ++qt) {
    const char* fq = fqd[qt & 1];

    // --- A: own prefetch(qt) drained, then all-waves barrier ---
    asm volatile("s_waitcnt vmcnt(0)" ::: "memory");
    __builtin_amdgcn_sched_barrier(0);
    __builtin_amdgcn_s_barrier();
    __builtin_amdgcn_sched_barrier(0);

    // --- B: issue fv fragment loads for this tile (8 asm loads, oldest) ---
    short8 av[2][4];
    #pragma unroll
    for (int kk = 0; kk < 2; ++kk)
      #pragma unroll
      for (int fi = 0; fi < 4; ++fi) {
        const char* pa = fvbase + (size_t)(w * 64 + fi * 16 + lr) * (HW * 2)
                         + qt * 128 + kk * 64 + lg * 16;
        asm volatile("global_load_dwordx4 %0, %1, off"
                     : "=&v"(av[kk][fi]) : "v"(pa) : "memory");
      }

    // --- C: issue prefetch of q-tile qt+1 into other buffer (8, newest) ---
    if (qt + 1 < NT) {
      const char* fsrc = fbase + (size_t)(qt + 1) * 32768;
      char* dbuf = (char*)fqd[(qt + 1) & 1];
      #pragma unroll
      for (int r = 0; r < 8; ++r)
        gl_lds16(fsrc + so[r], dbuf + (w * 8 + r) * 1024);
    }

    // --- D: GEMM1: S[p,q] = sum_c f_p f_q ---
    f32x4 s[2][2] = {};
    #pragma unroll
    for (int kk = 0; kk < 8; ++kk) {
      short8 bq[2];
      #pragma unroll
      for (int fj = 0; fj < 2; ++fj) {
        int q = wq * 32 + fj * 16 + lr;
        bq[fj] = *(const short8*)(fq + q * 512 + ((kk * 64 + lg * 16) ^ ((q & 7) << 4)));
      }
      s[0][0] = mfma16(ap[0][kk], bq[0], s[0][0]);
      s[0][1] = mfma16(ap[0][kk], bq[1], s[0][1]);
      s[1][0] = mfma16(ap[1][kk], bq[0], s[1][0]);
      s[1][1] = mfma16(ap[1][kk], bq[1], s[1][1]);
    }

    // --- E: relu^2 -> bf16 -> attl ---
    #pragma unroll
    for (int fi = 0; fi < 2; ++fi)
      #pragma unroll
      for (int fj = 0; fj < 2; ++fj)
        #pragma unroll
        for (int r = 0; r < 4; ++r) {
          float v = s[fi][fj][r];
          v = fmaxf(v, 0.f);
          v = v * v;
          int p = wp * 32 + fi * 16 + lg * 4 + r;
          int q = wq * 32 + fj * 16 + lr;
          *(u16*)(attl + p * 128 + ((q * 2) ^ ((p & 7) << 4))) = f2bf(v);
        }
    asm volatile("s_waitcnt lgkmcnt(0)" ::: "memory");
    __builtin_amdgcn_sched_barrier(0);
    __builtin_amdgcn_s_barrier();
    __builtin_amdgcn_sched_barrier(0);

    // --- F: retire the 8 av loads; keep the 8 prefetch loads in flight ---
    if (qt + 1 < NT) {
      asm volatile("s_waitcnt vmcnt(8)" ::: "memory");
    } else {
      asm volatile("s_waitcnt vmcnt(0)" ::: "memory");
    }
    __builtin_amdgcn_sched_barrier(0);

    // --- G: GEMM2: out[c,p] += sum_q FV[c,q] * ATT[p,q] ---
    #pragma unroll
    for (int kk = 0; kk < 2; ++kk) {
      short8 bt[4];
      #pragma unroll
      for (int fp = 0; fp < 4; ++fp) {
        int p = fp * 16 + lr;
        bt[fp] = *(const short8*)(attl + p * 128 + ((kk * 64 + lg * 16) ^ ((p & 7) << 4)));
      }
      #pragma unroll
      for (int fi = 0; fi < 4; ++fi)
        #pragma unroll
        for (int fp = 0; fp < 4; ++fp)
          oacc[fi][fp] = mfma16(av[kk][fi], bt[fp], oacc[fi][fp]);
    }
  }

  // epilogue: out[n][c][pt*64 + p]
  float* op = out + (size_t)n * CC * HW + pt * 64;
  #pragma unroll
  for (int fi = 0; fi < 4; ++fi)
    #pragma unroll
    for (int r = 0; r < 4; ++r) {
      int c = w * 64 + fi * 16 + lg * 4 + r;
      #pragma unroll
      for (int fp = 0; fp < 4; ++fp)
        op[(size_t)c * HW + fp * 16 + lr] = oacc[fi][fp][r];
    }
}

extern "C" void kernel_launch(void* const* d_in, const int* in_sizes, int n_in,
                              void* d_out, int out_size, void* d_ws, size_t ws_size,
                              hipStream_t stream) {
  const float* feat = (const float*)d_in[0];
  const float* W    = (const float*)d_in[1];
  const float* bias = (const float*)d_in[2];
  float* out = (float*)d_out;

  char* ws = (char*)d_ws;
  // ws layout: Wbf 128KB | norm_f 196KB | f_bf 24.5MB | fv_bf 24.5MB
  u16*   Wbf    = (u16*)ws;
  float* norm_f = (float*)(ws + 131072);
  u16*   f_bf   = (u16*)(ws + 331776);
  u16*   fv_bf  = (u16*)(ws + 26021888);

  k_cvtw<<<dim3(64), dim3(256), 0, stream>>>(W, Wbf);
  k_prep_f<<<dim3(NT, NB), dim3(256), 0, stream>>>(feat, f_bf, norm_f);
  k_conv<<<dim3(NT, NB), dim3(256), 0, stream>>>(Wbf, bias, f_bf, norm_f, fv_bf);
  k_attn<<<dim3(NT, NB), dim3(256), 0, stream>>>(f_bf, fv_bf, out);
}